// Round 11
// baseline (85.730 us; speedup 1.0000x reference)
//
#include <hip/hip_runtime.h>

#define NUM_WIRES 4
#define NUM_LAYERS 2

// R8 body (best verified: scalar f32, native HW trig, constants in SGPRs via
// float4-VMEM + readfirstlane) restructured as a grid-stride kernel:
// 1024 blocks x 256 threads, 4 elements/thread, software-pipelined x prefetch.
// Rationale: R4/R8/R9/R10 all pinned qsim at ~25us regardless of per-element
// instruction count -> per-wave fixed costs (constant prologue + cold x-load
// stall + wave spin-up) dominate. This amortizes them 4x and overlaps the
// next element's HBM load with the current element's ~1200-cycle body.
//
// ws layout (floats):
//  [ 0..15]  layer-0 per wire w: {A=cx*cz, B=cx*sz, C=sx*sz, D=sx*cz}
//  [16..23]  layer-1 RX per wire: {cos, sin}
//  [24..55]  layer-1 combined RZ diagonal: 16 x {dr, di}
//
// State layout: amp[i], bit3=wire0 ... bit0=wire3 (reference (B,2,2,2,2) order).

#define INV_4PI 0.07957747154594767f  // 0.5/(2*pi): sin(0.5x) = v_sin(x*INV_4PI)

__global__ void gate_prep(const float* __restrict__ params, float* __restrict__ g) {
    const int t = threadIdx.x;
    if (t < 4) {
        const float p0 = params[t * 2 + 0];  // RZ
        const float p1 = params[t * 2 + 1];  // RX
        float cz, sz, cx, sx;
        __sincosf(0.5f * p0, &sz, &cz);
        __sincosf(0.5f * p1, &sx, &cx);
        g[t * 4 + 0] = cx * cz;
        g[t * 4 + 1] = cx * sz;
        g[t * 4 + 2] = sx * sz;
        g[t * 4 + 3] = sx * cz;
    } else if (t < 8) {
        const int w = t - 4;
        const float p1 = params[(NUM_WIRES + w) * 2 + 1];
        float cx, sx;
        __sincosf(0.5f * p1, &sx, &cx);
        g[16 + w * 2] = cx;
        g[17 + w * 2] = sx;
    } else if (t >= 16 && t < 32) {
        const int i = t - 16;
        float dr = 1.f, di = 0.f;
        for (int w = 0; w < NUM_WIRES; ++w) {
            const float p0 = params[(NUM_WIRES + w) * 2 + 0];
            float c, s;
            __sincosf(0.5f * p0, &s, &c);
            const float sg = ((i >> (3 - w)) & 1) ? s : -s;
            const float ndr = dr * c - di * sg;
            const float ndi = dr * sg + di * c;
            dr = ndr; di = ndi;
        }
        g[24 + i * 2] = dr;
        g[25 + i * 2] = di;
    }
}

__device__ __forceinline__ float rfl(float v) {
    return __int_as_float(__builtin_amdgcn_readfirstlane(__float_as_int(v)));
}

__device__ __forceinline__ void cmul(float ar, float ai, float br, float bi,
                                     float& orr, float& oi) {
    orr = fmaf(ar, br, -(ai * bi));
    oi  = fmaf(ar, bi,   ai * br);
}

template <int CM, int TM>
__device__ __forceinline__ void cnot(float zr[16], float zi[16]) {
#pragma unroll
    for (int i = 0; i < 16; ++i) {
        if ((i & CM) && !(i & TM)) {
            const int j = i | TM;
            float t;
            t = zr[i]; zr[i] = zr[j]; zr[j] = t;
            t = zi[i]; zi[i] = zi[j]; zi[j] = t;
        }
    }
}

__device__ __forceinline__ float4 sim_one(const float4 xv, const float* __restrict__ G) {
    // Layer-0: fused gate applied to each wire's RY(x)|0> = (c,s) factor.
    float fr[4][2], fi[4][2];
    {
        const float xs[4] = {xv.x, xv.y, xv.z, xv.w};
#pragma unroll
        for (int w = 0; w < 4; ++w) {
            const float r = xs[w] * INV_4PI;
            const float s = __builtin_amdgcn_sinf(r);
            const float c = __builtin_amdgcn_cosf(r);
            const float A = G[w * 4 + 0], B = G[w * 4 + 1];
            const float C = G[w * 4 + 2], D = G[w * 4 + 3];
            fr[w][0] = fmaf(A, c, C * s);
            fi[w][0] = fmaf(-B, c, -(D * s));
            fr[w][1] = fmaf(A, s, -(C * c));
            fi[w][1] = fmaf(B, s, -(D * c));
        }
    }

    // Complex outer product: z = (f0 (x) f1) (x) (f2 (x) f3)
    float mr[4], mi[4], nr[4], ni[4];
#pragma unroll
    for (int p = 0; p < 2; ++p)
#pragma unroll
        for (int q = 0; q < 2; ++q) {
            cmul(fr[0][p], fi[0][p], fr[1][q], fi[1][q], mr[p * 2 + q], mi[p * 2 + q]);
            cmul(fr[2][p], fi[2][p], fr[3][q], fi[3][q], nr[p * 2 + q], ni[p * 2 + q]);
        }
    float zr[16], zi[16];
#pragma unroll
    for (int i = 0; i < 16; ++i)
        cmul(mr[i >> 2], mi[i >> 2], nr[i & 3], ni[i & 3], zr[i], zi[i]);

    // Layer-0 CNOT ring (free register permutation)
    cnot<8, 4>(zr, zi);
    cnot<4, 2>(zr, zi);
    cnot<2, 1>(zr, zi);
    cnot<1, 8>(zr, zi);

    // Layer-1 combined RZ diagonal
#pragma unroll
    for (int i = 0; i < 16; ++i) {
        const float dr = G[24 + i * 2], di = G[25 + i * 2];
        const float ar = zr[i], ai = zi[i];
        zr[i] = fmaf(dr, ar, -(di * ai));
        zi[i] = fmaf(dr, ai,   di * ar);
    }

    // Layer-1 RX per wire: new_a = c*a - i*s*b -> (c*ar + s*bi, c*ai - s*br)
#pragma unroll
    for (int w = 0; w < 4; ++w) {
        const float c = G[16 + w * 2], s = G[17 + w * 2];
        const int M = 8 >> w;
#pragma unroll
        for (int i = 0; i < 16; ++i) {
            if (!(i & M)) {
                const int j = i | M;
                const float ar = zr[i], ai = zi[i];
                const float br = zr[j], bi = zi[j];
                zr[i] = fmaf(c, ar,   s * bi);
                zi[i] = fmaf(c, ai, -(s * br));
                zr[j] = fmaf(c, br,   s * ai);
                zi[j] = fmaf(c, bi, -(s * ar));
            }
        }
    }

    // Layer-1 CNOT ring
    cnot<8, 4>(zr, zi);
    cnot<4, 2>(zr, zi);
    cnot<2, 1>(zr, zi);
    cnot<1, 8>(zr, zi);

    // Probabilities and <Z_w> via sum/difference tree
    float p[16];
#pragma unroll
    for (int i = 0; i < 16; ++i) p[i] = fmaf(zr[i], zr[i], zi[i] * zi[i]);

    float d0[8], s1[8];
#pragma unroll
    for (int k = 0; k < 8; ++k) {
        d0[k] = p[2 * k] - p[2 * k + 1];
        s1[k] = p[2 * k] + p[2 * k + 1];
    }
    const float e3 = ((d0[0] + d0[1]) + (d0[2] + d0[3])) + ((d0[4] + d0[5]) + (d0[6] + d0[7]));
    const float e2 = ((s1[0] - s1[1]) + (s1[2] - s1[3])) + ((s1[4] - s1[5]) + (s1[6] - s1[7]));
    float s2[4];
#pragma unroll
    for (int k = 0; k < 4; ++k) s2[k] = s1[2 * k] + s1[2 * k + 1];
    const float e1 = (s2[0] - s2[1]) + (s2[2] - s2[3]);
    const float e0 = (s2[0] + s2[1]) - (s2[2] + s2[3]);

    return make_float4(e0, e1, e2, e3);
}

__global__ __launch_bounds__(256) void qsim_kernel(const float* __restrict__ x,
                                                   const float* __restrict__ gf,
                                                   float* __restrict__ out, int batch) {
    // Prologue, paid ONCE per 4 elements: 56 wave-uniform constants -> SGPRs.
    float G[56];
#pragma unroll
    for (int k = 0; k < 14; ++k) {
        const float4 v = reinterpret_cast<const float4*>(gf)[k];
        G[4 * k + 0] = rfl(v.x);
        G[4 * k + 1] = rfl(v.y);
        G[4 * k + 2] = rfl(v.z);
        G[4 * k + 3] = rfl(v.w);
    }

    const int tid = threadIdx.x;
    const int base = blockIdx.x * 1024 + tid;  // block owns a contiguous 1024-chunk

    // Software-pipelined 4-element loop: prefetch next x during current body.
    int idx = base;
    float4 xcur = (idx < batch) ? reinterpret_cast<const float4*>(x)[idx]
                                : make_float4(0.f, 0.f, 0.f, 0.f);
#pragma clang loop unroll(disable)
    for (int k = 0; k < 4; ++k) {
        float4 xnext = xcur;
        const int idx_next = idx + 256;
        if (k < 3 && idx_next < batch)
            xnext = reinterpret_cast<const float4*>(x)[idx_next];

        const float4 r = sim_one(xcur, G);
        if (idx < batch)
            reinterpret_cast<float4*>(out)[idx] = r;

        xcur = xnext;
        idx = idx_next;
    }
}

extern "C" void kernel_launch(void* const* d_in, const int* in_sizes, int n_in,
                              void* d_out, int out_size, void* d_ws, size_t ws_size,
                              hipStream_t stream) {
    const float* x = (const float*)d_in[0];        // (B, 4) float32
    const float* params = (const float*)d_in[1];   // (2, 4, 2) float32
    float* out = (float*)d_out;                    // (B, 4) float32
    float* g = (float*)d_ws;                       // 56 floats of gate constants
    const int batch = in_sizes[0] / NUM_WIRES;

    gate_prep<<<1, 64, 0, stream>>>(params, g);
    const int blocks = (batch + 1023) / 1024;      // 4 elems/thread
    qsim_kernel<<<blocks, 256, 0, stream>>>(x, g, out, batch);
}

// Round 12
// 78.754 us; speedup vs baseline: 1.0886x; 1.0886x over previous
//
#include <hip/hip_runtime.h>

#define NUM_WIRES 4
#define NUM_LAYERS 2

// Single-kernel version: the gate_prep dispatch (1-block kernel + graph-node
// overhead + serialization with qsim, an untouched ~6-10us fixed cost in all
// prior rounds) is deleted. Each block redundantly computes the 56
// batch-uniform gate constants from params (threads 0..31, native HW trig)
// into LDS, barriers once, then uses the R4/R8-proven ds_read_b128 +
// readfirstlane -> SGPR path. Body is R8 verbatim (best: 77.96us).
//
// LDS layout (floats):
//  [ 0..15]  layer-0 per wire w: {A=cx*cz, B=cx*sz, C=sx*sz, D=sx*cz}
//  [16..23]  layer-1 RX per wire: {cos, sin}
//  [24..55]  layer-1 combined RZ diagonal: 16 x {dr, di}
//
// State layout: amp[i], bit3=wire0 ... bit0=wire3 (reference (B,2,2,2,2) order).

#define INV_4PI 0.07957747154594767f  // 0.5/(2*pi): sin(0.5x) = v_sin(x*INV_4PI)

__device__ __forceinline__ float rfl(float v) {
    return __int_as_float(__builtin_amdgcn_readfirstlane(__float_as_int(v)));
}

__device__ __forceinline__ void cmul(float ar, float ai, float br, float bi,
                                     float& orr, float& oi) {
    orr = fmaf(ar, br, -(ai * bi));
    oi  = fmaf(ar, bi,   ai * br);
}

template <int CM, int TM>
__device__ __forceinline__ void cnot(float zr[16], float zi[16]) {
#pragma unroll
    for (int i = 0; i < 16; ++i) {
        if ((i & CM) && !(i & TM)) {
            const int j = i | TM;
            float t;
            t = zr[i]; zr[i] = zr[j]; zr[j] = t;
            t = zi[i]; zi[i] = zi[j]; zi[j] = t;
        }
    }
}

__global__ __launch_bounds__(256) void qsim_kernel(const float* __restrict__ x,
                                                   const float* __restrict__ params,
                                                   float* __restrict__ out, int batch) {
    __shared__ float Ls[56];
    const int tid = threadIdx.x;

    // In-block gate prep (was a separate 1-block kernel in R1-R11).
    if (tid < 4) {
        const float p0 = params[tid * 2 + 0];  // RZ
        const float p1 = params[tid * 2 + 1];  // RX
        const float sz = __builtin_amdgcn_sinf(p0 * INV_4PI);
        const float cz = __builtin_amdgcn_cosf(p0 * INV_4PI);
        const float sx = __builtin_amdgcn_sinf(p1 * INV_4PI);
        const float cx = __builtin_amdgcn_cosf(p1 * INV_4PI);
        Ls[tid * 4 + 0] = cx * cz;
        Ls[tid * 4 + 1] = cx * sz;
        Ls[tid * 4 + 2] = sx * sz;
        Ls[tid * 4 + 3] = sx * cz;
    } else if (tid < 8) {
        const int w = tid - 4;
        const float p1 = params[(NUM_WIRES + w) * 2 + 1];
        Ls[16 + w * 2] = __builtin_amdgcn_cosf(p1 * INV_4PI);
        Ls[17 + w * 2] = __builtin_amdgcn_sinf(p1 * INV_4PI);
    } else if (tid >= 16 && tid < 32) {
        const int i = tid - 16;
        float dr = 1.f, di = 0.f;
        for (int w = 0; w < NUM_WIRES; ++w) {
            const float p0 = params[(NUM_WIRES + w) * 2 + 0];
            const float c = __builtin_amdgcn_cosf(p0 * INV_4PI);
            const float s = __builtin_amdgcn_sinf(p0 * INV_4PI);
            const float sg = ((i >> (3 - w)) & 1) ? s : -s;
            const float ndr = dr * c - di * sg;
            const float ndi = dr * sg + di * c;
            dr = ndr; di = ndi;
        }
        Ls[24 + i * 2] = dr;
        Ls[25 + i * 2] = di;
    }
    __syncthreads();

    // 56 wave-uniform constants -> SGPRs (broadcast ds_read, one rfl each).
    float G[56];
#pragma unroll
    for (int k = 0; k < 14; ++k) {
        const float4 v = reinterpret_cast<const float4*>(Ls)[k];
        G[4 * k + 0] = rfl(v.x);
        G[4 * k + 1] = rfl(v.y);
        G[4 * k + 2] = rfl(v.z);
        G[4 * k + 3] = rfl(v.w);
    }

    const int b = blockIdx.x * 256 + tid;
    if (b >= batch) return;

    const float4 xv = reinterpret_cast<const float4*>(x)[b];

    // Layer-0: fused gate applied to each wire's RY(x)|0> = (c,s) factor.
    float fr[4][2], fi[4][2];
    {
        const float xs[4] = {xv.x, xv.y, xv.z, xv.w};
#pragma unroll
        for (int w = 0; w < 4; ++w) {
            const float r = xs[w] * INV_4PI;
            const float s = __builtin_amdgcn_sinf(r);
            const float c = __builtin_amdgcn_cosf(r);
            const float A = G[w * 4 + 0], B = G[w * 4 + 1];
            const float C = G[w * 4 + 2], D = G[w * 4 + 3];
            fr[w][0] = fmaf(A, c, C * s);
            fi[w][0] = fmaf(-B, c, -(D * s));
            fr[w][1] = fmaf(A, s, -(C * c));
            fi[w][1] = fmaf(B, s, -(D * c));
        }
    }

    // Complex outer product: z = (f0 (x) f1) (x) (f2 (x) f3)
    float mr[4], mi[4], nr[4], ni[4];
#pragma unroll
    for (int p = 0; p < 2; ++p)
#pragma unroll
        for (int q = 0; q < 2; ++q) {
            cmul(fr[0][p], fi[0][p], fr[1][q], fi[1][q], mr[p * 2 + q], mi[p * 2 + q]);
            cmul(fr[2][p], fi[2][p], fr[3][q], fi[3][q], nr[p * 2 + q], ni[p * 2 + q]);
        }
    float zr[16], zi[16];
#pragma unroll
    for (int i = 0; i < 16; ++i)
        cmul(mr[i >> 2], mi[i >> 2], nr[i & 3], ni[i & 3], zr[i], zi[i]);

    // Layer-0 CNOT ring (free register permutation)
    cnot<8, 4>(zr, zi);
    cnot<4, 2>(zr, zi);
    cnot<2, 1>(zr, zi);
    cnot<1, 8>(zr, zi);

    // Layer-1 combined RZ diagonal
#pragma unroll
    for (int i = 0; i < 16; ++i) {
        const float dr = G[24 + i * 2], di = G[25 + i * 2];
        const float ar = zr[i], ai = zi[i];
        zr[i] = fmaf(dr, ar, -(di * ai));
        zi[i] = fmaf(dr, ai,   di * ar);
    }

    // Layer-1 RX per wire: new_a = c*a - i*s*b -> (c*ar + s*bi, c*ai - s*br)
#pragma unroll
    for (int w = 0; w < 4; ++w) {
        const float c = G[16 + w * 2], s = G[17 + w * 2];
        const int M = 8 >> w;
#pragma unroll
        for (int i = 0; i < 16; ++i) {
            if (!(i & M)) {
                const int j = i | M;
                const float ar = zr[i], ai = zi[i];
                const float br = zr[j], bi = zi[j];
                zr[i] = fmaf(c, ar,   s * bi);
                zi[i] = fmaf(c, ai, -(s * br));
                zr[j] = fmaf(c, br,   s * ai);
                zi[j] = fmaf(c, bi, -(s * ar));
            }
        }
    }

    // Layer-1 CNOT ring
    cnot<8, 4>(zr, zi);
    cnot<4, 2>(zr, zi);
    cnot<2, 1>(zr, zi);
    cnot<1, 8>(zr, zi);

    // Probabilities and <Z_w> via sum/difference tree
    float p[16];
#pragma unroll
    for (int i = 0; i < 16; ++i) p[i] = fmaf(zr[i], zr[i], zi[i] * zi[i]);

    float d0[8], s1[8];
#pragma unroll
    for (int k = 0; k < 8; ++k) {
        d0[k] = p[2 * k] - p[2 * k + 1];
        s1[k] = p[2 * k] + p[2 * k + 1];
    }
    const float e3 = ((d0[0] + d0[1]) + (d0[2] + d0[3])) + ((d0[4] + d0[5]) + (d0[6] + d0[7]));
    const float e2 = ((s1[0] - s1[1]) + (s1[2] - s1[3])) + ((s1[4] - s1[5]) + (s1[6] - s1[7]));
    float s2[4];
#pragma unroll
    for (int k = 0; k < 4; ++k) s2[k] = s1[2 * k] + s1[2 * k + 1];
    const float e1 = (s2[0] - s2[1]) + (s2[2] - s2[3]);
    const float e0 = (s2[0] + s2[1]) - (s2[2] + s2[3]);

    reinterpret_cast<float4*>(out)[b] = make_float4(e0, e1, e2, e3);
}

extern "C" void kernel_launch(void* const* d_in, const int* in_sizes, int n_in,
                              void* d_out, int out_size, void* d_ws, size_t ws_size,
                              hipStream_t stream) {
    const float* x = (const float*)d_in[0];        // (B, 4) float32
    const float* params = (const float*)d_in[1];   // (2, 4, 2) float32
    float* out = (float*)d_out;                    // (B, 4) float32
    const int batch = in_sizes[0] / NUM_WIRES;

    const int blocks = (batch + 255) / 256;
    qsim_kernel<<<blocks, 256, 0, stream>>>(x, params, out, batch);
}